// Round 1
// baseline (391.185 us; speedup 1.0000x reference)
//
#include <hip/hip_runtime.h>
#include <math.h>

#define NFIELDS 10
#define VOCAB   100000
#define EDIM    8
#define BATCH   16384
#define NPAIR   45   // 10*9/2

// One 64-lane wave per batch item.
// lanes [0,45): one (i,j) pair each -> dot(V[i,j,x[b,i],:], V[j,i,x[b,j],:])
// lanes [45,55): one first-order term each -> L[i, x[b,i]]
// full-wave shuffle reduction, lane 0 writes sigmoid(bias + sum).
__global__ __launch_bounds__(256) void ffm_kernel(
    const int*   __restrict__ x,     // (BATCH, NFIELDS)
    const float* __restrict__ bias,  // scalar
    const float* __restrict__ L,     // (NFIELDS, VOCAB)
    const float* __restrict__ V,     // (NFIELDS, NFIELDS, VOCAB, EDIM)
    float*       __restrict__ out)   // (BATCH, 1)
{
    const int lane = threadIdx.x & 63;
    const int wave = threadIdx.x >> 6;
    const int b    = blockIdx.x * 4 + wave;   // grid sized exactly: BATCH/4 blocks

    float acc = 0.0f;

    if (lane < NPAIR) {
        // linear pair index -> (i,j) with i<j (F=10): tiny loop, wave-uniform length
        int p = lane;
        int i = 0;
        int cnt = NFIELDS - 1;
        while (p >= cnt) { p -= cnt; ++i; --cnt; }
        const int j = i + 1 + p;

        const int xi = x[b * NFIELDS + i];
        const int xj = x[b * NFIELDS + j];

        const float* va = V + (((size_t)i * NFIELDS + j) * VOCAB + (size_t)xi) * EDIM;
        const float* vb = V + (((size_t)j * NFIELDS + i) * VOCAB + (size_t)xj) * EDIM;

        // rows are 32B-aligned -> float4 loads are legal
        const float4 a0 = ((const float4*)va)[0];
        const float4 a1 = ((const float4*)va)[1];
        const float4 b0 = ((const float4*)vb)[0];
        const float4 b1 = ((const float4*)vb)[1];

        acc = a0.x * b0.x + a0.y * b0.y + a0.z * b0.z + a0.w * b0.w
            + a1.x * b1.x + a1.y * b1.y + a1.z * b1.z + a1.w * b1.w;
    } else if (lane < NPAIR + NFIELDS) {
        const int i  = lane - NPAIR;
        const int xi = x[b * NFIELDS + i];
        acc = L[(size_t)i * VOCAB + (size_t)xi];
    }

    // 64-lane butterfly sum
    #pragma unroll
    for (int off = 32; off > 0; off >>= 1)
        acc += __shfl_down(acc, off, 64);

    if (lane == 0) {
        const float logit = acc + bias[0];
        out[b] = 1.0f / (1.0f + expf(-logit));
    }
}

extern "C" void kernel_launch(void* const* d_in, const int* in_sizes, int n_in,
                              void* d_out, int out_size, void* d_ws, size_t ws_size,
                              hipStream_t stream) {
    const int*   x    = (const int*)  d_in[0];
    const float* bias = (const float*)d_in[1];
    const float* L    = (const float*)d_in[2];
    const float* V    = (const float*)d_in[3];
    float*       out  = (float*)d_out;

    const int blocks = BATCH / 4;   // 4 waves (items) per 256-thread block
    ffm_kernel<<<blocks, 256, 0, stream>>>(x, bias, L, V, out);
}